// Round 1
// baseline (5711.946 us; speedup 1.0000x reference)
//
#include <hip/hip_runtime.h>
#include <hip/hip_bf16.h>

// GraphMatchingLayer: edge MLP (160->64 relu, 64->64) + scatter-add on row +
// node MLP (128->64 relu, 64->64).  All fp32.
//
// Baseline design (round 0):
//  - thread-per-edge / thread-per-node, acc[64] in registers
//  - weights in LDS, read as wave-broadcast ds_read_b128 (conflict-free)
//  - layer-2 h[k] dynamic indexing via private LDS column (no barriers needed)
//  - scatter via unsafeAtomicAdd f32 (global_atomic_add_f32)

#define TPB 256

// ---- layer-1 segment: NCH float4 chunks from SRCPTR, k-offset KB, weights SW ----
#define SEG_L1(SRCPTR, NCH, KB, SW, ACC)                                      \
  for (int kc = 0; kc < (NCH); ++kc) {                                        \
    const float4 a_ = (SRCPTR)[kc];                                           \
    const float av_[4] = {a_.x, a_.y, a_.z, a_.w};                            \
    _Pragma("unroll")                                                         \
    for (int j_ = 0; j_ < 4; ++j_) {                                          \
      const float ak_ = av_[j_];                                              \
      const float4* wr_ = (const float4*)((SW) + ((KB) + kc * 4 + j_) * 64);  \
      _Pragma("unroll")                                                       \
      for (int c4_ = 0; c4_ < 16; ++c4_) {                                    \
        const float4 w_ = wr_[c4_];                                           \
        ACC[c4_ * 4 + 0] = fmaf(ak_, w_.x, ACC[c4_ * 4 + 0]);                 \
        ACC[c4_ * 4 + 1] = fmaf(ak_, w_.y, ACC[c4_ * 4 + 1]);                 \
        ACC[c4_ * 4 + 2] = fmaf(ak_, w_.z, ACC[c4_ * 4 + 2]);                 \
        ACC[c4_ * 4 + 3] = fmaf(ak_, w_.w, ACC[c4_ * 4 + 3]);                 \
      }                                                                       \
    }                                                                         \
  }

// ---- layer-2: relu(ACC) @ SW2 + SB2 -> M.  h staged through private LDS col ----
#define LAYER2(SW2, SB2, ACC, M, HBUF, TID)                                   \
  {                                                                           \
    const float4* bv_ = (const float4*)(SB2);                                 \
    _Pragma("unroll")                                                         \
    for (int c4_ = 0; c4_ < 16; ++c4_) {                                      \
      const float4 b_ = bv_[c4_];                                             \
      M[c4_ * 4 + 0] = b_.x; M[c4_ * 4 + 1] = b_.y;                           \
      M[c4_ * 4 + 2] = b_.z; M[c4_ * 4 + 3] = b_.w;                           \
    }                                                                         \
    float* hcol_ = (HBUF) + (TID);                                            \
    _Pragma("unroll")                                                         \
    for (int q_ = 0; q_ < 4; ++q_) {                                          \
      _Pragma("unroll")                                                       \
      for (int kk_ = 0; kk_ < 16; ++kk_)                                      \
        hcol_[kk_ * 257] = fmaxf(ACC[q_ * 16 + kk_], 0.f);                    \
      for (int kk_ = 0; kk_ < 16; ++kk_) {                                    \
        const float hk_ = hcol_[kk_ * 257];                                   \
        const float4* wr_ = (const float4*)((SW2) + (q_ * 16 + kk_) * 64);    \
        _Pragma("unroll")                                                     \
        for (int c4_ = 0; c4_ < 16; ++c4_) {                                  \
          const float4 w_ = wr_[c4_];                                         \
          M[c4_ * 4 + 0] = fmaf(hk_, w_.x, M[c4_ * 4 + 0]);                   \
          M[c4_ * 4 + 1] = fmaf(hk_, w_.y, M[c4_ * 4 + 1]);                   \
          M[c4_ * 4 + 2] = fmaf(hk_, w_.z, M[c4_ * 4 + 2]);                   \
          M[c4_ * 4 + 3] = fmaf(hk_, w_.w, M[c4_ * 4 + 3]);                   \
        }                                                                     \
      }                                                                       \
    }                                                                         \
  }

__global__ __launch_bounds__(TPB, 2)
void gml_edge_kernel(const float* __restrict__ x,
                     const int* __restrict__ ei,
                     const float* __restrict__ ea,
                     const float* __restrict__ w1,
                     const float* __restrict__ b1,
                     const float* __restrict__ w2,
                     const float* __restrict__ b2,
                     float* __restrict__ agg,
                     int E)
{
  __shared__ float sw1[160 * 64];      // 40960 B
  __shared__ float sw2[64 * 64];       // 16384 B
  __shared__ float sb1[64];
  __shared__ float sb2[64];
  __shared__ float hbuf[16 * 257];     // 16448 B  (private column per thread)

  const int tid = threadIdx.x;
  {
    const float4* s1 = (const float4*)w1;
    float4* d1 = (float4*)sw1;
    for (int i = tid; i < 160 * 64 / 4; i += TPB) d1[i] = s1[i];
    const float4* s2 = (const float4*)w2;
    float4* d2 = (float4*)sw2;
    for (int i = tid; i < 64 * 64 / 4; i += TPB) d2[i] = s2[i];
    if (tid < 64) { sb1[tid] = b1[tid]; sb2[tid] = b2[tid]; }
  }
  __syncthreads();

  const int e = blockIdx.x * TPB + tid;
  if (e >= E) return;

  const int r = ei[e];
  const int c = ei[E + e];

  float acc[64];
  {
    const float4* bv = (const float4*)sb1;
    #pragma unroll
    for (int c4 = 0; c4 < 16; ++c4) {
      const float4 b = bv[c4];
      acc[c4 * 4 + 0] = b.x; acc[c4 * 4 + 1] = b.y;
      acc[c4 * 4 + 2] = b.z; acc[c4 * 4 + 3] = b.w;
    }
  }

  const float4* xr = (const float4*)(x + (size_t)r * 64);
  const float4* xc = (const float4*)(x + (size_t)c * 64);
  const float4* ev = (const float4*)(ea + (size_t)e * 32);

  SEG_L1(xr, 16, 0,   sw1, acc)
  SEG_L1(xc, 16, 64,  sw1, acc)
  SEG_L1(ev, 8,  128, sw1, acc)

  float m[64];
  LAYER2(sw2, sb2, acc, m, hbuf, tid)

  float* ag = agg + (size_t)r * 64;
  #pragma unroll
  for (int cc = 0; cc < 64; ++cc) unsafeAtomicAdd(ag + cc, m[cc]);
}

__global__ __launch_bounds__(TPB, 2)
void gml_node_kernel(const float* __restrict__ x,
                     const float* __restrict__ agg,
                     const float* __restrict__ w1,
                     const float* __restrict__ b1,
                     const float* __restrict__ w2,
                     const float* __restrict__ b2,
                     float* __restrict__ out,
                     int N)
{
  __shared__ float sw1[128 * 64];      // 32768 B
  __shared__ float sw2[64 * 64];       // 16384 B
  __shared__ float sb1[64];
  __shared__ float sb2[64];
  __shared__ float hbuf[16 * 257];     // 16448 B

  const int tid = threadIdx.x;
  {
    const float4* s1 = (const float4*)w1;
    float4* d1 = (float4*)sw1;
    for (int i = tid; i < 128 * 64 / 4; i += TPB) d1[i] = s1[i];
    const float4* s2 = (const float4*)w2;
    float4* d2 = (float4*)sw2;
    for (int i = tid; i < 64 * 64 / 4; i += TPB) d2[i] = s2[i];
    if (tid < 64) { sb1[tid] = b1[tid]; sb2[tid] = b2[tid]; }
  }
  __syncthreads();

  const int n = blockIdx.x * TPB + tid;
  if (n >= N) return;

  float acc[64];
  {
    const float4* bv = (const float4*)sb1;
    #pragma unroll
    for (int c4 = 0; c4 < 16; ++c4) {
      const float4 b = bv[c4];
      acc[c4 * 4 + 0] = b.x; acc[c4 * 4 + 1] = b.y;
      acc[c4 * 4 + 2] = b.z; acc[c4 * 4 + 3] = b.w;
    }
  }

  const float4* xv = (const float4*)(x + (size_t)n * 64);
  const float4* av = (const float4*)(agg + (size_t)n * 64);

  SEG_L1(xv, 16, 0,  sw1, acc)
  SEG_L1(av, 16, 64, sw1, acc)

  float m[64];
  LAYER2(sw2, sb2, acc, m, hbuf, tid)

  float4* ov = (float4*)(out + (size_t)n * 64);
  #pragma unroll
  for (int c4 = 0; c4 < 16; ++c4)
    ov[c4] = make_float4(m[c4 * 4 + 0], m[c4 * 4 + 1], m[c4 * 4 + 2], m[c4 * 4 + 3]);
}

extern "C" void kernel_launch(void* const* d_in, const int* in_sizes, int n_in,
                              void* d_out, int out_size, void* d_ws, size_t ws_size,
                              hipStream_t stream) {
  const float* x   = (const float*)d_in[0];
  const int*   ei  = (const int*)d_in[1];
  const float* ea  = (const float*)d_in[2];
  const float* ew1 = (const float*)d_in[3];
  const float* eb1 = (const float*)d_in[4];
  const float* ew2 = (const float*)d_in[5];
  const float* eb2 = (const float*)d_in[6];
  const float* nw1 = (const float*)d_in[7];
  const float* nb1 = (const float*)d_in[8];
  const float* nw2 = (const float*)d_in[9];
  const float* nb2 = (const float*)d_in[10];
  float* out = (float*)d_out;

  const int N = in_sizes[0] / 64;   // 100000
  const int E = in_sizes[1] / 2;    // 1600000

  float* agg = (float*)d_ws;        // N*64 f32 = 25.6 MB scratch

  hipMemsetAsync(agg, 0, (size_t)N * 64 * sizeof(float), stream);

  gml_edge_kernel<<<(E + TPB - 1) / TPB, TPB, 0, stream>>>(
      x, ei, ea, ew1, eb1, ew2, eb2, agg, E);

  gml_node_kernel<<<(N + TPB - 1) / TPB, TPB, 0, stream>>>(
      x, agg, nw1, nb1, nw2, nb2, out, N);
}

// Round 2
// 2322.843 us; speedup vs baseline: 2.4590x; 2.4590x over previous
//
#include <hip/hip_runtime.h>
#include <hip/hip_bf16.h>

// GraphMatchingLayer, round 2: atomic-free via on-device CSR + fused
// per-node gather-compute. Weights read from GLOBAL with wave-uniform
// addresses -> s_load into SGPRs (scalar pipe), no LDS weight staging.
//
//  k_hist          deg[row[e]]++                    (int atomics, cheap)
//  k_scan          exclusive scan deg -> start,cur; 64-bucket degree hist
//  k_bscan         bucket scan (1 thread)
//  k_scatter_edges eid[cur[row]++] = e              (CSR edge lists)
//  k_scatter_nodes nodeperm sorted by degree        (wave load balance)
//  k_fused         2 threads per node (even/odd edges), agg[64] in regs,
//                  shfl_xor merge, node MLP, no atomics, no msg buffer.

#define TPB 256

// ---- layer-1 segment: NCH float4 chunks from SRC (per-lane addr), weights
// ---- W read from global with uniform address -> scalar loads
#define SEG_G(SRC, NCH, KB, W, ACC)                                     \
  for (int kc_ = 0; kc_ < (NCH); ++kc_) {                               \
    const float4 a_ = ((const float4*)(SRC))[kc_];                      \
    const float av_[4] = {a_.x, a_.y, a_.z, a_.w};                      \
    _Pragma("unroll")                                                   \
    for (int j_ = 0; j_ < 4; ++j_) {                                    \
      const float ak_ = av_[j_];                                        \
      const float* wr_ = (W) + ((KB) + kc_ * 4 + j_) * 64;              \
      _Pragma("unroll")                                                 \
      for (int cc_ = 0; cc_ < 64; ++cc_)                                \
        ACC[cc_] = fmaf(ak_, wr_[cc_], ACC[cc_]);                       \
    }                                                                   \
  }

// ---- 64 register inputs (expression of q_,kk_) routed through a private
// ---- LDS column so the k-loop can stay dynamic (no scratch, small code)
#define SEGH(W, KB, SRCEXPR, ACC, HCOL)                                 \
  _Pragma("unroll")                                                     \
  for (int q_ = 0; q_ < 4; ++q_) {                                      \
    _Pragma("unroll")                                                   \
    for (int kk_ = 0; kk_ < 16; ++kk_)                                  \
      (HCOL)[kk_ * 257] = (SRCEXPR);                                    \
    for (int kk_ = 0; kk_ < 16; ++kk_) {                                \
      const float ak_ = (HCOL)[kk_ * 257];                              \
      const float* wr_ = (W) + ((KB) + q_ * 16 + kk_) * 64;             \
      _Pragma("unroll")                                                 \
      for (int cc_ = 0; cc_ < 64; ++cc_)                                \
        ACC[cc_] = fmaf(ak_, wr_[cc_], ACC[cc_]);                       \
    }                                                                   \
  }

__global__ __launch_bounds__(TPB)
void k_hist(const int* __restrict__ ei, int* __restrict__ deg, int E) {
  int e = blockIdx.x * TPB + threadIdx.x;
  if (e < E) atomicAdd(&deg[ei[e]], 1);
}

__global__ __launch_bounds__(1024)
void k_scan(const int* __restrict__ deg, int* __restrict__ start,
            int* __restrict__ cur, int* __restrict__ bcnt, int N) {
  __shared__ int ssum[1024];
  __shared__ int sb[64];
  const int tid = threadIdx.x;
  if (tid < 64) sb[tid] = 0;
  __syncthreads();
  const int C = (N + 1023) / 1024;
  const int lo = tid * C;
  const int hi = min(lo + C, N);
  int s = 0;
  for (int i = lo; i < hi; ++i) {
    int d = deg[i];
    s += d;
    atomicAdd(&sb[min(d, 63)], 1);
  }
  ssum[tid] = s;
  __syncthreads();
  for (int off = 1; off < 1024; off <<= 1) {
    int v = (tid >= off) ? ssum[tid - off] : 0;
    __syncthreads();
    ssum[tid] += v;
    __syncthreads();
  }
  int excl = (tid == 0) ? 0 : ssum[tid - 1];
  for (int i = lo; i < hi; ++i) {
    int d = deg[i];
    start[i] = excl;
    cur[i] = excl;
    excl += d;
  }
  if (tid == 0) start[N] = ssum[1023];
  if (tid < 64) bcnt[tid] = sb[tid];
}

__global__ void k_bscan(const int* __restrict__ bcnt, int* __restrict__ bstart,
                        int* __restrict__ bcur) {
  if (threadIdx.x < 64) bcur[threadIdx.x] = 0;
  if (threadIdx.x == 0) {
    int a = 0;
    for (int i = 0; i < 64; ++i) { bstart[i] = a; a += bcnt[i]; }
    bstart[64] = a;
  }
}

__global__ __launch_bounds__(TPB)
void k_scatter_edges(const int* __restrict__ ei, int* __restrict__ cur,
                     int* __restrict__ eid, int E) {
  int e = blockIdx.x * TPB + threadIdx.x;
  if (e < E) {
    int p = atomicAdd(&cur[ei[e]], 1);
    eid[p] = e;
  }
}

__global__ __launch_bounds__(TPB)
void k_scatter_nodes(const int* __restrict__ deg, const int* __restrict__ bstart,
                     int* __restrict__ bcur, int* __restrict__ nodeperm, int N) {
  int n = blockIdx.x * TPB + threadIdx.x;
  if (n < N) {
    int b = min(deg[n], 63);
    int p = atomicAdd(&bcur[b], 1);
    nodeperm[bstart[b] + p] = n;
  }
}

__global__ __launch_bounds__(TPB, 2)
void k_fused(const float* __restrict__ x,
             const int* __restrict__ ei,
             const float* __restrict__ ea,
             const float* __restrict__ ew1, const float* __restrict__ eb1,
             const float* __restrict__ ew2, const float* __restrict__ eb2,
             const float* __restrict__ nw1, const float* __restrict__ nb1,
             const float* __restrict__ nw2, const float* __restrict__ nb2,
             const int* __restrict__ start, const int* __restrict__ eid,
             const int* __restrict__ nodeperm,
             float* __restrict__ out, int N, int E)
{
  __shared__ float hbuf[16 * 257];            // private column per thread
  const int tid = threadIdx.x;
  const int t = blockIdx.x * TPB + tid;
  if (t >= 2 * N) return;
  const int n = nodeperm[t >> 1];
  const int half = t & 1;

  float* hcol = hbuf + tid;

  float agg[64];
  #pragma unroll
  for (int c = 0; c < 64; ++c) agg[c] = 0.f;

  const int s0 = start[n];
  const int s1 = start[n + 1];
  const float* xn = x + (size_t)n * 64;

  int nedge = 0;
  for (int i = s0 + half; i < s1; i += 2) {
    ++nedge;
    const int e = eid[i];
    const int c = ei[E + e];
    const float* xc = x + (size_t)c * 64;
    const float* eav = ea + (size_t)e * 32;

    float acc[64];
    #pragma unroll
    for (int q = 0; q < 64; ++q) acc[q] = 0.f;

    SEG_G(xn,  16, 0,   ew1, acc)
    SEG_G(xc,  16, 64,  ew1, acc)
    SEG_G(eav, 8,  128, ew1, acc)

    // layer 2: agg += relu(acc + b1) @ ew2   (b2 hoisted out of the loop)
    SEGH(ew2, 0, fmaxf(acc[q_ * 16 + kk_] + eb1[q_ * 16 + kk_], 0.f), agg, hcol)
  }

  {
    // hoisted: each message also contributes +eb2
    const float degf = (float)nedge;
    #pragma unroll
    for (int c = 0; c < 64; ++c) agg[c] = fmaf(degf, eb2[c], agg[c]);
  }

  // merge the two half-aggregates; both lanes end with the full sum
  #pragma unroll
  for (int c = 0; c < 64; ++c) agg[c] += __shfl_xor(agg[c], 1);

  // node MLP: concat [x[n], agg] @ nw1 + nb1 -> relu -> @ nw2 + nb2
  float nacc[64];
  #pragma unroll
  for (int q = 0; q < 64; ++q) nacc[q] = 0.f;

  SEG_G(xn, 16, 0, nw1, nacc)
  SEGH(nw1, 64, agg[q_ * 16 + kk_], nacc, hcol)

  // reuse agg as output accumulator
  #pragma unroll
  for (int c = 0; c < 64; ++c) agg[c] = nb2[c];
  SEGH(nw2, 0, fmaxf(nacc[q_ * 16 + kk_] + nb1[q_ * 16 + kk_], 0.f), agg, hcol)

  // both lanes of the pair computed identical values; identical double-store is benign
  float4* ov = (float4*)(out + (size_t)n * 64);
  #pragma unroll
  for (int c4 = 0; c4 < 16; ++c4)
    ov[c4] = make_float4(agg[c4 * 4 + 0], agg[c4 * 4 + 1],
                         agg[c4 * 4 + 2], agg[c4 * 4 + 3]);
}

extern "C" void kernel_launch(void* const* d_in, const int* in_sizes, int n_in,
                              void* d_out, int out_size, void* d_ws, size_t ws_size,
                              hipStream_t stream) {
  const float* x   = (const float*)d_in[0];
  const int*   ei  = (const int*)d_in[1];
  const float* ea  = (const float*)d_in[2];
  const float* ew1 = (const float*)d_in[3];
  const float* eb1 = (const float*)d_in[4];
  const float* ew2 = (const float*)d_in[5];
  const float* eb2 = (const float*)d_in[6];
  const float* nw1 = (const float*)d_in[7];
  const float* nb1 = (const float*)d_in[8];
  const float* nw2 = (const float*)d_in[9];
  const float* nb2 = (const float*)d_in[10];
  float* out = (float*)d_out;

  const int N = in_sizes[0] / 64;   // 100000
  const int E = in_sizes[1] / 2;    // 1600000

  // workspace layout (ints)
  int* ws       = (int*)d_ws;
  int* deg      = ws;                    // N
  int* bcnt     = ws + N;                // 64   (contiguous with deg for one memset)
  int* start    = ws + N + 64;           // N+1
  int* cur      = ws + 2 * N + 65;       // N
  int* bstart   = ws + 3 * N + 65;       // 65
  int* bcur     = ws + 3 * N + 130;      // 64
  int* nodeperm = ws + 3 * N + 194;      // N
  int* eid      = ws + 4 * N + 194;      // E

  hipMemsetAsync(deg, 0, (size_t)(N + 64) * sizeof(int), stream);

  k_hist<<<(E + TPB - 1) / TPB, TPB, 0, stream>>>(ei, deg, E);
  k_scan<<<1, 1024, 0, stream>>>(deg, start, cur, bcnt, N);
  k_bscan<<<1, 64, 0, stream>>>(bcnt, bstart, bcur);
  k_scatter_edges<<<(E + TPB - 1) / TPB, TPB, 0, stream>>>(ei, cur, eid, E);
  k_scatter_nodes<<<(N + TPB - 1) / TPB, TPB, 0, stream>>>(deg, bstart, bcur, nodeperm, N);

  k_fused<<<(2 * N + TPB - 1) / TPB, TPB, 0, stream>>>(
      x, ei, ea, ew1, eb1, ew2, eb2, nw1, nb1, nw2, nb2,
      start, eid, nodeperm, out, N, E);
}

// Round 3
// 1175.159 us; speedup vs baseline: 4.8606x; 1.9766x over previous
//
#include <hip/hip_runtime.h>
#include <hip/hip_bf16.h>

// GraphMatchingLayer, round 3: thread-per-CSR-position edge phase with
// wave-level segmented reduction (plain stores for wave-interior rows,
// atomics only at wave-boundary segments), multi-block scan, solo node MLP.

#define TPB 256

// ---- layer-1 segment: NCH float4 chunks from SRC (per-lane addr), weights
// ---- W read from global with wave-uniform address -> scalar loads
#define SEG_G(SRC, NCH, KB, W, ACC)                                     \
  for (int kc_ = 0; kc_ < (NCH); ++kc_) {                               \
    const float4 a_ = ((const float4*)(SRC))[kc_];                      \
    const float av_[4] = {a_.x, a_.y, a_.z, a_.w};                      \
    _Pragma("unroll")                                                   \
    for (int j_ = 0; j_ < 4; ++j_) {                                    \
      const float ak_ = av_[j_];                                        \
      const float* wr_ = (W) + ((KB) + kc_ * 4 + j_) * 64;              \
      _Pragma("unroll")                                                 \
      for (int cc_ = 0; cc_ < 64; ++cc_)                                \
        ACC[cc_] = fmaf(ak_, wr_[cc_], ACC[cc_]);                       \
    }                                                                   \
  }

// ---- layer-2: 64 per-thread register inputs (expr of q_,kk_) routed through
// ---- a private LDS column (stride 257 -> 2-way=free banks) so k stays dynamic
#define SEGH(W, KB, SRCEXPR, ACC, HCOL)                                 \
  _Pragma("unroll")                                                     \
  for (int q_ = 0; q_ < 4; ++q_) {                                      \
    _Pragma("unroll")                                                   \
    for (int kk_ = 0; kk_ < 16; ++kk_)                                  \
      (HCOL)[kk_ * 257] = (SRCEXPR);                                    \
    for (int kk_ = 0; kk_ < 16; ++kk_) {                                \
      const float ak_ = (HCOL)[kk_ * 257];                              \
      const float* wr_ = (W) + ((KB) + q_ * 16 + kk_) * 64;             \
      _Pragma("unroll")                                                 \
      for (int cc_ = 0; cc_ < 64; ++cc_)                                \
        ACC[cc_] = fmaf(ak_, wr_[cc_], ACC[cc_]);                       \
    }                                                                   \
  }

// ---------------- CSR build ----------------

__global__ __launch_bounds__(TPB)
void k_hist(const int* __restrict__ ei, int* __restrict__ deg, int E) {
  int e = blockIdx.x * TPB + threadIdx.x;
  if (e < E) atomicAdd(&deg[ei[e]], 1);
}

// each scan thread owns 4 nodes
__global__ __launch_bounds__(TPB)
void k_red(const int* __restrict__ deg, int* __restrict__ bsum, int N) {
  __shared__ int s[TPB];
  const int tid = threadIdx.x;
  const int g = (blockIdx.x * TPB + tid) * 4;
  int v = 0;
  #pragma unroll
  for (int j = 0; j < 4; ++j) if (g + j < N) v += deg[g + j];
  s[tid] = v;
  __syncthreads();
  for (int off = TPB / 2; off > 0; off >>= 1) {
    if (tid < off) s[tid] += s[tid + off];
    __syncthreads();
  }
  if (tid == 0) bsum[blockIdx.x] = s[0];
}

__global__ void k_scanb(const int* __restrict__ bsum, int* __restrict__ boff, int NB) {
  if (threadIdx.x == 0) {
    int a = 0;
    for (int i = 0; i < NB; ++i) { boff[i] = a; a += bsum[i]; }
  }
}

__global__ __launch_bounds__(TPB)
void k_apply(const int* __restrict__ deg, const int* __restrict__ boff,
             int* __restrict__ cur, int N) {
  __shared__ int s[TPB];
  const int tid = threadIdx.x;
  const int g = (blockIdx.x * TPB + tid) * 4;
  int d[4];
  int v = 0;
  #pragma unroll
  for (int j = 0; j < 4; ++j) { d[j] = (g + j < N) ? deg[g + j] : 0; v += d[j]; }
  s[tid] = v;
  __syncthreads();
  for (int off = 1; off < TPB; off <<= 1) {
    int t = (tid >= off) ? s[tid - off] : 0;
    __syncthreads();
    s[tid] += t;
    __syncthreads();
  }
  int base = boff[blockIdx.x] + s[tid] - v;   // exclusive prefix for this thread
  #pragma unroll
  for (int j = 0; j < 4; ++j)
    if (g + j < N) { cur[g + j] = base; base += d[j]; }
}

__global__ __launch_bounds__(TPB)
void k_scatter(const int* __restrict__ ei, int* __restrict__ cur,
               int* __restrict__ eid, int* __restrict__ rid, int E) {
  int e = blockIdx.x * TPB + threadIdx.x;
  if (e < E) {
    int r = ei[e];
    int p = atomicAdd(&cur[r], 1);
    eid[p] = e;
    rid[p] = r;
  }
}

// ---------------- edge phase: one thread per CSR position ----------------

__global__ __launch_bounds__(TPB)
void k_edge(const float* __restrict__ x,
            const int* __restrict__ ei,
            const float* __restrict__ ea,
            const float* __restrict__ ew1, const float* __restrict__ eb1,
            const float* __restrict__ ew2, const float* __restrict__ eb2,
            const int* __restrict__ eid, const int* __restrict__ rid,
            float* __restrict__ agg, int E)
{
  __shared__ float hbuf[16 * 257];
  const int tid = threadIdx.x;
  const int lane = tid & 63;
  const int p = blockIdx.x * TPB + tid;
  float* hcol = hbuf + tid;

  int r = -1;
  float m[64];
  #pragma unroll
  for (int c = 0; c < 64; ++c) m[c] = 0.f;

  if (p < E) {
    const int e = eid[p];
    r = rid[p];
    const int cidx = ei[E + e];

    float acc[64];
    #pragma unroll
    for (int c = 0; c < 64; ++c) acc[c] = eb1[c];

    SEG_G(x + (size_t)r * 64,    16, 0,   ew1, acc)
    SEG_G(x + (size_t)cidx * 64, 16, 64,  ew1, acc)
    SEG_G(ea + (size_t)e * 32,   8,  128, ew1, acc)

    #pragma unroll
    for (int c = 0; c < 64; ++c) m[c] = eb2[c];
    SEGH(ew2, 0, fmaxf(acc[q_ * 16 + kk_], 0.f), m, hcol)
  }

  // ---- wave-level segmented inclusive sum of m[] keyed by r ----
  const int rprev = __shfl_up(r, 1);
  const bool head = (lane == 0) || (r != rprev);
  const unsigned long long hm = __ballot(head);
  const unsigned long long below = hm & (~0ULL >> (63 - lane));
  const int ss = 63 - __clzll(below);          // my segment's start lane

  #pragma unroll
  for (int off = 1; off < 64; off <<= 1) {
    const bool take = (lane - ss) >= off;
    #pragma unroll
    for (int c = 0; c < 64; ++c) {
      const float t = __shfl_up(m[c], off);
      if (take) m[c] += t;
    }
  }

  const int rnext = __shfl_down(r, 1);
  const bool is_end = (lane == 63) || (r != rnext);

  if (p < E && is_end) {
    float* ag = agg + (size_t)r * 64;
    if (ss == 0 || lane == 63) {
      // segment may continue in a neighboring wave -> atomic
      #pragma unroll
      for (int c = 0; c < 64; ++c) unsafeAtomicAdd(ag + c, m[c]);
    } else {
      // row fully contained in this wave -> sole writer, plain stores
      float4* a4 = (float4*)ag;
      #pragma unroll
      for (int c4 = 0; c4 < 16; ++c4)
        a4[c4] = make_float4(m[c4 * 4 + 0], m[c4 * 4 + 1],
                             m[c4 * 4 + 2], m[c4 * 4 + 3]);
    }
  }
}

// ---------------- node MLP: one thread per node ----------------

__global__ __launch_bounds__(TPB)
void k_node(const float* __restrict__ x, const float* __restrict__ agg,
            const float* __restrict__ nw1, const float* __restrict__ nb1,
            const float* __restrict__ nw2, const float* __restrict__ nb2,
            float* __restrict__ out, int N)
{
  __shared__ float hbuf[16 * 257];
  const int tid = threadIdx.x;
  const int n = blockIdx.x * TPB + tid;
  if (n >= N) return;
  float* hcol = hbuf + tid;

  float acc[64];
  #pragma unroll
  for (int c = 0; c < 64; ++c) acc[c] = nb1[c];

  SEG_G(x + (size_t)n * 64,   16, 0,  nw1, acc)
  SEG_G(agg + (size_t)n * 64, 16, 64, nw1, acc)

  float m[64];
  #pragma unroll
  for (int c = 0; c < 64; ++c) m[c] = nb2[c];
  SEGH(nw2, 0, fmaxf(acc[q_ * 16 + kk_], 0.f), m, hcol)

  float4* ov = (float4*)(out + (size_t)n * 64);
  #pragma unroll
  for (int c4 = 0; c4 < 16; ++c4)
    ov[c4] = make_float4(m[c4 * 4 + 0], m[c4 * 4 + 1],
                         m[c4 * 4 + 2], m[c4 * 4 + 3]);
}

extern "C" void kernel_launch(void* const* d_in, const int* in_sizes, int n_in,
                              void* d_out, int out_size, void* d_ws, size_t ws_size,
                              hipStream_t stream) {
  const float* x   = (const float*)d_in[0];
  const int*   ei  = (const int*)d_in[1];
  const float* ea  = (const float*)d_in[2];
  const float* ew1 = (const float*)d_in[3];
  const float* eb1 = (const float*)d_in[4];
  const float* ew2 = (const float*)d_in[5];
  const float* eb2 = (const float*)d_in[6];
  const float* nw1 = (const float*)d_in[7];
  const float* nb1 = (const float*)d_in[8];
  const float* nw2 = (const float*)d_in[9];
  const float* nb2 = (const float*)d_in[10];
  float* out = (float*)d_out;

  const int N = in_sizes[0] / 64;   // 100000
  const int E = in_sizes[1] / 2;    // 1600000

  // workspace layout
  float* agg = (float*)d_ws;                       // N*64 f32 = 25.6 MB
  int* ib    = (int*)(agg + (size_t)N * 64);
  int* deg   = ib;                                 // N
  int* cur   = ib + N;                             // N
  int* bsum  = ib + 2 * N;                         // <=512
  int* boff  = ib + 2 * N + 512;                   // <=512
  int* eid   = ib + 2 * N + 1024;                  // E
  int* rid   = eid + E;                            // E

  const int NT = (N + 3) / 4;                      // scan threads
  const int NB = (NT + TPB - 1) / TPB;             // scan blocks (98)

  hipMemsetAsync(agg, 0, (size_t)N * 64 * sizeof(float), stream);
  hipMemsetAsync(deg, 0, (size_t)N * sizeof(int), stream);

  k_hist<<<(E + TPB - 1) / TPB, TPB, 0, stream>>>(ei, deg, E);
  k_red<<<NB, TPB, 0, stream>>>(deg, bsum, N);
  k_scanb<<<1, 64, 0, stream>>>(bsum, boff, NB);
  k_apply<<<NB, TPB, 0, stream>>>(deg, boff, cur, N);
  k_scatter<<<(E + TPB - 1) / TPB, TPB, 0, stream>>>(ei, cur, eid, rid, E);

  k_edge<<<(E + TPB - 1) / TPB, TPB, 0, stream>>>(
      x, ei, ea, ew1, eb1, ew2, eb2, eid, rid, agg, E);

  k_node<<<(N + TPB - 1) / TPB, TPB, 0, stream>>>(
      x, agg, nw1, nb1, nw2, nb2, out, N);
}

// Round 4
// 763.449 us; speedup vs baseline: 7.4818x; 1.5393x over previous
//
#include <hip/hip_runtime.h>
#include <hip/hip_bf16.h>

// GraphMatchingLayer, round 4: algebraic refactor.
//   edge_features@ew1 = x[r]@W1a + x[c]@W1b + ea@W1c  -> precompute U=x@W1a+b1, V=x@W1b per NODE
//   segment_sum(h@ew2+b2) = (segment_sum h)@ew2 + deg*b2 -> per-node GEMM on H
// Edge kernel now: gather U[r] (segment-broadcast) + V[c] (random) + ea@W1c (2048 FMA),
// relu, wave-segmented sum -> H (stored in d_out), zero LDS.
// Node kernel: agg = H@ew2 + deg*b2; out = relu([x,agg]@nw1+nb1)@nw2+nb2, in-place over d_out.
// Falls back to the proven round-3 path if ws_size is too small.

#define TPB 256

// ---- dense segment: NCH float4 chunks from SRC (per-lane addr), weights W
// ---- read from global with wave-uniform address -> scalar loads
#define SEG_G(SRC, NCH, KB, W, ACC)                                     \
  for (int kc_ = 0; kc_ < (NCH); ++kc_) {                               \
    const float4 a_ = ((const float4*)(SRC))[kc_];                      \
    const float av_[4] = {a_.x, a_.y, a_.z, a_.w};                      \
    _Pragma("unroll")                                                   \
    for (int j_ = 0; j_ < 4; ++j_) {                                    \
      const float ak_ = av_[j_];                                        \
      const float* wr_ = (W) + ((KB) + kc_ * 4 + j_) * 64;              \
      _Pragma("unroll")                                                 \
      for (int cc_ = 0; cc_ < 64; ++cc_)                                \
        ACC[cc_] = fmaf(ak_, wr_[cc_], ACC[cc_]);                       \
    }                                                                   \
  }

// ---- 64 per-thread register inputs (expr of q_,kk_) routed through a
// ---- private LDS column so the k index stays dynamic (no scratch)
#define SEGH(W, KB, SRCEXPR, ACC, HCOL)                                 \
  _Pragma("unroll")                                                     \
  for (int q_ = 0; q_ < 4; ++q_) {                                      \
    _Pragma("unroll")                                                   \
    for (int kk_ = 0; kk_ < 16; ++kk_)                                  \
      (HCOL)[kk_ * 257] = (SRCEXPR);                                    \
    for (int kk_ = 0; kk_ < 16; ++kk_) {                                \
      const float ak_ = (HCOL)[kk_ * 257];                              \
      const float* wr_ = (W) + ((KB) + q_ * 16 + kk_) * 64;             \
      _Pragma("unroll")                                                 \
      for (int cc_ = 0; cc_ < 64; ++cc_)                                \
        ACC[cc_] = fmaf(ak_, wr_[cc_], ACC[cc_]);                       \
    }                                                                   \
  }

// ---------------- CSR build (round-3, proven) ----------------

__global__ __launch_bounds__(TPB)
void k_hist(const int* __restrict__ ei, int* __restrict__ deg, int E) {
  int e = blockIdx.x * TPB + threadIdx.x;
  if (e < E) atomicAdd(&deg[ei[e]], 1);
}

__global__ __launch_bounds__(TPB)
void k_red(const int* __restrict__ deg, int* __restrict__ bsum, int N) {
  __shared__ int s[TPB];
  const int tid = threadIdx.x;
  const int g = (blockIdx.x * TPB + tid) * 4;
  int v = 0;
  #pragma unroll
  for (int j = 0; j < 4; ++j) if (g + j < N) v += deg[g + j];
  s[tid] = v;
  __syncthreads();
  for (int off = TPB / 2; off > 0; off >>= 1) {
    if (tid < off) s[tid] += s[tid + off];
    __syncthreads();
  }
  if (tid == 0) bsum[blockIdx.x] = s[0];
}

__global__ void k_scanb(const int* __restrict__ bsum, int* __restrict__ boff, int NB) {
  if (threadIdx.x == 0) {
    int a = 0;
    for (int i = 0; i < NB; ++i) { boff[i] = a; a += bsum[i]; }
  }
}

__global__ __launch_bounds__(TPB)
void k_apply(const int* __restrict__ deg, const int* __restrict__ boff,
             int* __restrict__ cur, int N) {
  __shared__ int s[TPB];
  const int tid = threadIdx.x;
  const int g = (blockIdx.x * TPB + tid) * 4;
  int d[4];
  int v = 0;
  #pragma unroll
  for (int j = 0; j < 4; ++j) { d[j] = (g + j < N) ? deg[g + j] : 0; v += d[j]; }
  s[tid] = v;
  __syncthreads();
  for (int off = 1; off < TPB; off <<= 1) {
    int t = (tid >= off) ? s[tid - off] : 0;
    __syncthreads();
    s[tid] += t;
    __syncthreads();
  }
  int base = boff[blockIdx.x] + s[tid] - v;
  #pragma unroll
  for (int j = 0; j < 4; ++j)
    if (g + j < N) { cur[g + j] = base; base += d[j]; }
}

__global__ __launch_bounds__(TPB)
void k_scatter(const int* __restrict__ ei, int* __restrict__ cur,
               int* __restrict__ eid, int* __restrict__ rid, int E) {
  int e = blockIdx.x * TPB + threadIdx.x;
  if (e < E) {
    int r = ei[e];
    int p = atomicAdd(&cur[r], 1);
    eid[p] = e;
    rid[p] = r;
  }
}

// ---------------- round-4 main path ----------------

// U[n] = x[n]@ew1[0:64] + eb1 ;  V[n] = x[n]@ew1[64:128]
__global__ __launch_bounds__(TPB)
void k_prep(const float* __restrict__ x,
            const float* __restrict__ ew1, const float* __restrict__ eb1,
            float* __restrict__ U, float* __restrict__ V, int N)
{
  const int n = blockIdx.x * TPB + threadIdx.x;
  if (n >= N) return;
  const float* xn = x + (size_t)n * 64;

  float acc[64];
  #pragma unroll
  for (int c = 0; c < 64; ++c) acc[c] = eb1[c];
  SEG_G(xn, 16, 0, ew1, acc)
  float4* u4 = (float4*)(U + (size_t)n * 64);
  #pragma unroll
  for (int c4 = 0; c4 < 16; ++c4)
    u4[c4] = make_float4(acc[c4*4+0], acc[c4*4+1], acc[c4*4+2], acc[c4*4+3]);

  #pragma unroll
  for (int c = 0; c < 64; ++c) acc[c] = 0.f;
  SEG_G(xn, 16, 0, ew1 + 64 * 64, acc)
  float4* v4 = (float4*)(V + (size_t)n * 64);
  #pragma unroll
  for (int c4 = 0; c4 < 16; ++c4)
    v4[c4] = make_float4(acc[c4*4+0], acc[c4*4+1], acc[c4*4+2], acc[c4*4+3]);
}

// per CSR position: h = relu(U[r] + V[c] + ea[e]@W1c); wave-segmented sum -> H
__global__ __launch_bounds__(TPB)
void k_edge2(const float* __restrict__ U, const float* __restrict__ V,
             const int* __restrict__ ei, const float* __restrict__ ea,
             const float* __restrict__ ew1,
             const int* __restrict__ eid, const int* __restrict__ rid,
             float* __restrict__ H, int E)
{
  const int tid = threadIdx.x;
  const int lane = tid & 63;
  const int p = blockIdx.x * TPB + tid;

  int r = -1;
  float m[64];
  #pragma unroll
  for (int c = 0; c < 64; ++c) m[c] = 0.f;

  if (p < E) {
    const int e = eid[p];
    r = rid[p];
    const int cidx = ei[E + e];

    const float4* u4 = (const float4*)(U + (size_t)r * 64);
    const float4* v4 = (const float4*)(V + (size_t)cidx * 64);
    #pragma unroll
    for (int c4 = 0; c4 < 16; ++c4) {
      const float4 a = u4[c4];
      const float4 b = v4[c4];
      m[c4*4+0] = a.x + b.x; m[c4*4+1] = a.y + b.y;
      m[c4*4+2] = a.z + b.z; m[c4*4+3] = a.w + b.w;
    }
    SEG_G(ea + (size_t)e * 32, 8, 0, ew1 + 128 * 64, m)
    #pragma unroll
    for (int c = 0; c < 64; ++c) m[c] = fmaxf(m[c], 0.f);
  }

  // ---- wave-level segmented inclusive sum keyed by r ----
  const int rprev = __shfl_up(r, 1);
  const bool head = (lane == 0) || (r != rprev);
  const unsigned long long hm = __ballot(head);
  const unsigned long long below = hm & (~0ULL >> (63 - lane));
  const int ss = 63 - __clzll(below);

  #pragma unroll
  for (int off = 1; off < 64; off <<= 1) {
    const bool take = (lane - ss) >= off;
    #pragma unroll
    for (int c = 0; c < 64; ++c) {
      const float t = __shfl_up(m[c], off);
      if (take) m[c] += t;
    }
  }

  const int rnext = __shfl_down(r, 1);
  const bool is_end = (lane == 63) || (r != rnext);

  if (p < E && is_end) {
    float* hg = H + (size_t)r * 64;
    if (ss == 0 || lane == 63) {
      #pragma unroll
      for (int c = 0; c < 64; ++c) unsafeAtomicAdd(hg + c, m[c]);
    } else {
      float4* h4 = (float4*)hg;
      #pragma unroll
      for (int c4 = 0; c4 < 16; ++c4)
        h4[c4] = make_float4(m[c4*4+0], m[c4*4+1], m[c4*4+2], m[c4*4+3]);
    }
  }
}

// agg = H@ew2 + deg*eb2; out = relu([x,agg]@nw1 + nb1)@nw2 + nb2  (in-place over H)
__global__ __launch_bounds__(TPB)
void k_node2(const float* __restrict__ x, const float* __restrict__ Hin,
             const int* __restrict__ deg,
             const float* __restrict__ ew2, const float* __restrict__ eb2,
             const float* __restrict__ nw1, const float* __restrict__ nb1,
             const float* __restrict__ nw2, const float* __restrict__ nb2,
             float* __restrict__ out, int N)
{
  __shared__ float hbuf[16 * 257];
  const int tid = threadIdx.x;
  const int n = blockIdx.x * TPB + tid;
  if (n >= N) return;
  float* hcol = hbuf + tid;

  float hrow[64];
  {
    const float4* h4 = (const float4*)(Hin + (size_t)n * 64);
    #pragma unroll
    for (int c4 = 0; c4 < 16; ++c4) {
      const float4 a = h4[c4];
      hrow[c4*4+0] = a.x; hrow[c4*4+1] = a.y; hrow[c4*4+2] = a.z; hrow[c4*4+3] = a.w;
    }
  }
  const float dg = (float)deg[n];

  float agg[64];
  #pragma unroll
  for (int c = 0; c < 64; ++c) agg[c] = dg * eb2[c];
  SEGH(ew2, 0, hrow[q_ * 16 + kk_], agg, hcol)

  float acc[64];
  #pragma unroll
  for (int c = 0; c < 64; ++c) acc[c] = nb1[c];
  SEG_G(x + (size_t)n * 64, 16, 0, nw1, acc)
  SEGH(nw1, 64, agg[q_ * 16 + kk_], acc, hcol)

  float o[64];
  #pragma unroll
  for (int c = 0; c < 64; ++c) o[c] = nb2[c];
  SEGH(nw2, 0, fmaxf(acc[q_ * 16 + kk_], 0.f), o, hcol)

  float4* ov = (float4*)(out + (size_t)n * 64);
  #pragma unroll
  for (int c4 = 0; c4 < 16; ++c4)
    ov[c4] = make_float4(o[c4*4+0], o[c4*4+1], o[c4*4+2], o[c4*4+3]);
}

// ---------------- round-3 fallback path (small ws) ----------------

__global__ __launch_bounds__(TPB)
void k_edge_fb(const float* __restrict__ x,
               const int* __restrict__ ei,
               const float* __restrict__ ea,
               const float* __restrict__ ew1, const float* __restrict__ eb1,
               const float* __restrict__ ew2, const float* __restrict__ eb2,
               const int* __restrict__ eid, const int* __restrict__ rid,
               float* __restrict__ agg, int E)
{
  __shared__ float hbuf[16 * 257];
  const int tid = threadIdx.x;
  const int lane = tid & 63;
  const int p = blockIdx.x * TPB + tid;
  float* hcol = hbuf + tid;

  int r = -1;
  float m[64];
  #pragma unroll
  for (int c = 0; c < 64; ++c) m[c] = 0.f;

  if (p < E) {
    const int e = eid[p];
    r = rid[p];
    const int cidx = ei[E + e];

    float acc[64];
    #pragma unroll
    for (int c = 0; c < 64; ++c) acc[c] = eb1[c];
    SEG_G(x + (size_t)r * 64,    16, 0,   ew1, acc)
    SEG_G(x + (size_t)cidx * 64, 16, 64,  ew1, acc)
    SEG_G(ea + (size_t)e * 32,   8,  128, ew1, acc)

    #pragma unroll
    for (int c = 0; c < 64; ++c) m[c] = eb2[c];
    SEGH(ew2, 0, fmaxf(acc[q_ * 16 + kk_], 0.f), m, hcol)
  }

  const int rprev = __shfl_up(r, 1);
  const bool head = (lane == 0) || (r != rprev);
  const unsigned long long hm = __ballot(head);
  const unsigned long long below = hm & (~0ULL >> (63 - lane));
  const int ss = 63 - __clzll(below);

  #pragma unroll
  for (int off = 1; off < 64; off <<= 1) {
    const bool take = (lane - ss) >= off;
    #pragma unroll
    for (int c = 0; c < 64; ++c) {
      const float t = __shfl_up(m[c], off);
      if (take) m[c] += t;
    }
  }

  const int rnext = __shfl_down(r, 1);
  const bool is_end = (lane == 63) || (r != rnext);

  if (p < E && is_end) {
    float* ag = agg + (size_t)r * 64;
    if (ss == 0 || lane == 63) {
      #pragma unroll
      for (int c = 0; c < 64; ++c) unsafeAtomicAdd(ag + c, m[c]);
    } else {
      float4* a4 = (float4*)ag;
      #pragma unroll
      for (int c4 = 0; c4 < 16; ++c4)
        a4[c4] = make_float4(m[c4*4+0], m[c4*4+1], m[c4*4+2], m[c4*4+3]);
    }
  }
}

__global__ __launch_bounds__(TPB)
void k_node_fb(const float* __restrict__ x, const float* __restrict__ agg,
               const float* __restrict__ nw1, const float* __restrict__ nb1,
               const float* __restrict__ nw2, const float* __restrict__ nb2,
               float* __restrict__ out, int N)
{
  __shared__ float hbuf[16 * 257];
  const int tid = threadIdx.x;
  const int n = blockIdx.x * TPB + tid;
  if (n >= N) return;
  float* hcol = hbuf + tid;

  float acc[64];
  #pragma unroll
  for (int c = 0; c < 64; ++c) acc[c] = nb1[c];
  SEG_G(x + (size_t)n * 64,   16, 0,  nw1, acc)
  SEG_G(agg + (size_t)n * 64, 16, 64, nw1, acc)

  float m[64];
  #pragma unroll
  for (int c = 0; c < 64; ++c) m[c] = nb2[c];
  SEGH(nw2, 0, fmaxf(acc[q_ * 16 + kk_], 0.f), m, hcol)

  float4* ov = (float4*)(out + (size_t)n * 64);
  #pragma unroll
  for (int c4 = 0; c4 < 16; ++c4)
    ov[c4] = make_float4(m[c4*4+0], m[c4*4+1], m[c4*4+2], m[c4*4+3]);
}

// ---------------- launch ----------------

extern "C" void kernel_launch(void* const* d_in, const int* in_sizes, int n_in,
                              void* d_out, int out_size, void* d_ws, size_t ws_size,
                              hipStream_t stream) {
  const float* x   = (const float*)d_in[0];
  const int*   ei  = (const int*)d_in[1];
  const float* ea  = (const float*)d_in[2];
  const float* ew1 = (const float*)d_in[3];
  const float* eb1 = (const float*)d_in[4];
  const float* ew2 = (const float*)d_in[5];
  const float* eb2 = (const float*)d_in[6];
  const float* nw1 = (const float*)d_in[7];
  const float* nb1 = (const float*)d_in[8];
  const float* nw2 = (const float*)d_in[9];
  const float* nb2 = (const float*)d_in[10];
  float* out = (float*)d_out;

  const int N = in_sizes[0] / 64;   // 100000
  const int E = in_sizes[1] / 2;    // 1600000

  const int NT = (N + 3) / 4;
  const int NB = (NT + TPB - 1) / TPB;

  const size_t need_new = 2 * (size_t)N * 64 * 4                 // U, V
                        + ((size_t)2 * N + 1024 + 2 * (size_t)E) * 4;  // CSR

  if (ws_size >= need_new) {
    float* U  = (float*)d_ws;                       // N*64
    float* V  = U + (size_t)N * 64;                 // N*64
    int* ib   = (int*)(V + (size_t)N * 64);
    int* deg  = ib;
    int* cur  = ib + N;
    int* bsum = ib + 2 * N;
    int* boff = ib + 2 * N + 512;
    int* eid  = ib + 2 * N + 1024;
    int* rid  = eid + E;
    float* H  = out;                                // H lives in d_out

    hipMemsetAsync(deg, 0, (size_t)N * sizeof(int), stream);
    hipMemsetAsync(H, 0, (size_t)N * 64 * sizeof(float), stream);

    k_hist<<<(E + TPB - 1) / TPB, TPB, 0, stream>>>(ei, deg, E);
    k_red<<<NB, TPB, 0, stream>>>(deg, bsum, N);
    k_scanb<<<1, 64, 0, stream>>>(bsum, boff, NB);
    k_apply<<<NB, TPB, 0, stream>>>(deg, boff, cur, N);
    k_scatter<<<(E + TPB - 1) / TPB, TPB, 0, stream>>>(ei, cur, eid, rid, E);

    k_prep<<<(N + TPB - 1) / TPB, TPB, 0, stream>>>(x, ew1, eb1, U, V, N);

    k_edge2<<<(E + TPB - 1) / TPB, TPB, 0, stream>>>(
        U, V, ei, ea, ew1, eid, rid, H, E);

    k_node2<<<(N + TPB - 1) / TPB, TPB, 0, stream>>>(
        x, H, deg, ew2, eb2, nw1, nb1, nw2, nb2, out, N);
  } else {
    // round-3 fallback
    float* agg = (float*)d_ws;                      // N*64
    int* ib    = (int*)(agg + (size_t)N * 64);
    int* deg   = ib;
    int* cur   = ib + N;
    int* bsum  = ib + 2 * N;
    int* boff  = ib + 2 * N + 512;
    int* eid   = ib + 2 * N + 1024;
    int* rid   = eid + E;

    hipMemsetAsync(agg, 0, (size_t)N * 64 * sizeof(float), stream);
    hipMemsetAsync(deg, 0, (size_t)N * sizeof(int), stream);

    k_hist<<<(E + TPB - 1) / TPB, TPB, 0, stream>>>(ei, deg, E);
    k_red<<<NB, TPB, 0, stream>>>(deg, bsum, N);
    k_scanb<<<1, 64, 0, stream>>>(bsum, boff, NB);
    k_apply<<<NB, TPB, 0, stream>>>(deg, boff, cur, N);
    k_scatter<<<(E + TPB - 1) / TPB, TPB, 0, stream>>>(ei, cur, eid, rid, E);

    k_edge_fb<<<(E + TPB - 1) / TPB, TPB, 0, stream>>>(
        x, ei, ea, ew1, eb1, ew2, eb2, eid, rid, agg, E);

    k_node_fb<<<(N + TPB - 1) / TPB, TPB, 0, stream>>>(
        x, agg, nw1, nb1, nw2, nb2, out, N);
  }
}

// Round 5
// 634.201 us; speedup vs baseline: 9.0065x; 1.2038x over previous
//
#include <hip/hip_runtime.h>
#include <hip/hip_bf16.h>

// GraphMatchingLayer, round 5:
//  - k_edge3: ONE WAVE PER NODE, lane = output channel. No scan, no atomics.
//    W1c column in 32 VGPRs/lane; e/c/ea[e] wave-uniform -> scalar (s_load)
//    broadcast; V[c]/U[n]/H[n] rows coalesced. H = d_out (no memset).
//  - k_prep2: U/V split across wave-uniform halves (2x waves vs round 4).
//  - CSR build as round 4 minus rid.
//  - k_node2 unchanged (target for round 6 if it shows in top-5).

#define TPB 256

// ---- dense segment: NCH float4 chunks from SRC (per-lane addr), weights W
// ---- read from global with wave-uniform address -> scalar loads
#define SEG_G(SRC, NCH, KB, W, ACC)                                     \
  for (int kc_ = 0; kc_ < (NCH); ++kc_) {                               \
    const float4 a_ = ((const float4*)(SRC))[kc_];                      \
    const float av_[4] = {a_.x, a_.y, a_.z, a_.w};                      \
    _Pragma("unroll")                                                   \
    for (int j_ = 0; j_ < 4; ++j_) {                                    \
      const float ak_ = av_[j_];                                        \
      const float* wr_ = (W) + ((KB) + kc_ * 4 + j_) * 64;              \
      _Pragma("unroll")                                                 \
      for (int cc_ = 0; cc_ < 64; ++cc_)                                \
        ACC[cc_] = fmaf(ak_, wr_[cc_], ACC[cc_]);                       \
    }                                                                   \
  }

// ---- 64 per-thread register inputs (expr of q_,kk_) routed through a
// ---- private LDS column so the k index stays dynamic (no scratch)
#define SEGH(W, KB, SRCEXPR, ACC, HCOL)                                 \
  _Pragma("unroll")                                                     \
  for (int q_ = 0; q_ < 4; ++q_) {                                      \
    _Pragma("unroll")                                                   \
    for (int kk_ = 0; kk_ < 16; ++kk_)                                  \
      (HCOL)[kk_ * 257] = (SRCEXPR);                                    \
    for (int kk_ = 0; kk_ < 16; ++kk_) {                                \
      const float ak_ = (HCOL)[kk_ * 257];                              \
      const float* wr_ = (W) + ((KB) + q_ * 16 + kk_) * 64;             \
      _Pragma("unroll")                                                 \
      for (int cc_ = 0; cc_ < 64; ++cc_)                                \
        ACC[cc_] = fmaf(ak_, wr_[cc_], ACC[cc_]);                       \
    }                                                                   \
  }

// ---------------- CSR build ----------------

__global__ __launch_bounds__(TPB)
void k_hist(const int* __restrict__ ei, int* __restrict__ deg, int E) {
  int e = blockIdx.x * TPB + threadIdx.x;
  if (e < E) atomicAdd(&deg[ei[e]], 1);
}

__global__ __launch_bounds__(TPB)
void k_red(const int* __restrict__ deg, int* __restrict__ bsum, int N) {
  __shared__ int s[TPB];
  const int tid = threadIdx.x;
  const int g = (blockIdx.x * TPB + tid) * 4;
  int v = 0;
  #pragma unroll
  for (int j = 0; j < 4; ++j) if (g + j < N) v += deg[g + j];
  s[tid] = v;
  __syncthreads();
  for (int off = TPB / 2; off > 0; off >>= 1) {
    if (tid < off) s[tid] += s[tid + off];
    __syncthreads();
  }
  if (tid == 0) bsum[blockIdx.x] = s[0];
}

__global__ void k_scanb(const int* __restrict__ bsum, int* __restrict__ boff, int NB) {
  if (threadIdx.x == 0) {
    int a = 0;
    for (int i = 0; i < NB; ++i) { boff[i] = a; a += bsum[i]; }
  }
}

__global__ __launch_bounds__(TPB)
void k_apply(const int* __restrict__ deg, const int* __restrict__ boff,
             int* __restrict__ cur, int N) {
  __shared__ int s[TPB];
  const int tid = threadIdx.x;
  const int g = (blockIdx.x * TPB + tid) * 4;
  int d[4];
  int v = 0;
  #pragma unroll
  for (int j = 0; j < 4; ++j) { d[j] = (g + j < N) ? deg[g + j] : 0; v += d[j]; }
  s[tid] = v;
  __syncthreads();
  for (int off = 1; off < TPB; off <<= 1) {
    int t = (tid >= off) ? s[tid - off] : 0;
    __syncthreads();
    s[tid] += t;
    __syncthreads();
  }
  int base = boff[blockIdx.x] + s[tid] - v;
  #pragma unroll
  for (int j = 0; j < 4; ++j)
    if (g + j < N) { cur[g + j] = base; base += d[j]; }
}

__global__ __launch_bounds__(TPB)
void k_scatter(const int* __restrict__ ei, int* __restrict__ cur,
               int* __restrict__ eid, int E) {
  int e = blockIdx.x * TPB + threadIdx.x;
  if (e < E) {
    int p = atomicAdd(&cur[ei[e]], 1);
    eid[p] = e;
  }
}

// ---------------- U/V precompute: wave-uniform half split ----------------
// wave w: half = w&1 (0 -> U = x@W1a + b1, 1 -> V = x@W1b), node = (w>>1)*64 + lane

__global__ __launch_bounds__(TPB)
void k_prep2(const float* __restrict__ x,
             const float* __restrict__ ew1, const float* __restrict__ eb1,
             float* __restrict__ U, float* __restrict__ V, int N)
{
  const int t = blockIdx.x * TPB + threadIdx.x;
  const int w = __builtin_amdgcn_readfirstlane(t >> 6);
  const int lane = t & 63;
  const int half = w & 1;
  const int n = (w >> 1) * 64 + lane;
  if (n >= N) return;

  const float* xn = x + (size_t)n * 64;
  const float* W = ew1 + (half ? 64 * 64 : 0);

  float acc[64];
  if (half) {
    #pragma unroll
    for (int c = 0; c < 64; ++c) acc[c] = 0.f;
  } else {
    #pragma unroll
    for (int c = 0; c < 64; ++c) acc[c] = eb1[c];
  }
  SEG_G(xn, 16, 0, W, acc)

  float* dst = (half ? V : U) + (size_t)n * 64;
  float4* d4 = (float4*)dst;
  #pragma unroll
  for (int c4 = 0; c4 < 16; ++c4)
    d4[c4] = make_float4(acc[c4*4+0], acc[c4*4+1], acc[c4*4+2], acc[c4*4+3]);
}

// ---------------- edge phase: one wave per node, lane = channel ----------------

__global__ __launch_bounds__(TPB)
void k_edge3(const float* __restrict__ U, const float* __restrict__ V,
             const float* __restrict__ ea, const int* __restrict__ ei,
             const float* __restrict__ ew1,
             const int* __restrict__ deg, const int* __restrict__ cur,
             const int* __restrict__ eid,
             float* __restrict__ H, int N, int E)
{
  const int lane = threadIdx.x & 63;
  const int wid  = __builtin_amdgcn_readfirstlane(threadIdx.x >> 6);
  const int n    = __builtin_amdgcn_readfirstlane((int)blockIdx.x * 4 + wid);
  if (n >= N) return;

  const int d  = __builtin_amdgcn_readfirstlane(deg[n]);
  const int s0 = __builtin_amdgcn_readfirstlane(cur[n]) - d;

  // this lane's W1c column: w[k] = W1c[k][lane]  (coalesced, loaded once)
  float w[32];
  #pragma unroll
  for (int k = 0; k < 32; ++k) w[k] = ew1[(128 + k) * 64 + lane];

  const float u = U[(size_t)n * 64 + lane];
  float acc = 0.f;

  // one-ahead rotation of the wave-uniform (e, c) scalar chain
  int e0 = 0, c0 = 0;
  if (d > 0) {
    e0 = __builtin_amdgcn_readfirstlane(eid[s0]);
    c0 = __builtin_amdgcn_readfirstlane(ei[E + e0]);
  }

  for (int i = 0; i < d; ++i) {
    const int e = e0, c = c0;
    if (i + 1 < d) {
      e0 = __builtin_amdgcn_readfirstlane(eid[s0 + i + 1]);
      c0 = __builtin_amdgcn_readfirstlane(ei[E + e0]);
    }
    const float vv = V[(size_t)c * 64 + lane];          // coalesced row
    const float* eap = ea + (size_t)e * 32;             // wave-uniform -> s_load
    float t0 = u + vv, t1 = 0.f, t2 = 0.f, t3 = 0.f;
    #pragma unroll
    for (int k = 0; k < 32; k += 4) {
      t0 = fmaf(eap[k + 0], w[k + 0], t0);
      t1 = fmaf(eap[k + 1], w[k + 1], t1);
      t2 = fmaf(eap[k + 2], w[k + 2], t2);
      t3 = fmaf(eap[k + 3], w[k + 3], t3);
    }
    acc += fmaxf((t0 + t1) + (t2 + t3), 0.f);
  }

  H[(size_t)n * 64 + lane] = acc;                       // every node written
}

// ---------------- node MLP (round-4, scalar) ----------------

__global__ __launch_bounds__(TPB)
void k_node2(const float* __restrict__ x, const float* __restrict__ Hin,
             const int* __restrict__ deg,
             const float* __restrict__ ew2, const float* __restrict__ eb2,
             const float* __restrict__ nw1, const float* __restrict__ nb1,
             const float* __restrict__ nw2, const float* __restrict__ nb2,
             float* __restrict__ out, int N)
{
  __shared__ float hbuf[16 * 257];
  const int tid = threadIdx.x;
  const int n = blockIdx.x * TPB + tid;
  if (n >= N) return;
  float* hcol = hbuf + tid;

  float hrow[64];
  {
    const float4* h4 = (const float4*)(Hin + (size_t)n * 64);
    #pragma unroll
    for (int c4 = 0; c4 < 16; ++c4) {
      const float4 a = h4[c4];
      hrow[c4*4+0] = a.x; hrow[c4*4+1] = a.y; hrow[c4*4+2] = a.z; hrow[c4*4+3] = a.w;
    }
  }
  const float dg = (float)deg[n];

  float agg[64];
  #pragma unroll
  for (int c = 0; c < 64; ++c) agg[c] = dg * eb2[c];
  SEGH(ew2, 0, hrow[q_ * 16 + kk_], agg, hcol)

  float acc[64];
  #pragma unroll
  for (int c = 0; c < 64; ++c) acc[c] = nb1[c];
  SEG_G(x + (size_t)n * 64, 16, 0, nw1, acc)
  SEGH(nw1, 64, agg[q_ * 16 + kk_], acc, hcol)

  float o[64];
  #pragma unroll
  for (int c = 0; c < 64; ++c) o[c] = nb2[c];
  SEGH(nw2, 0, fmaxf(acc[q_ * 16 + kk_], 0.f), o, hcol)

  float4* ov = (float4*)(out + (size_t)n * 64);
  #pragma unroll
  for (int c4 = 0; c4 < 16; ++c4)
    ov[c4] = make_float4(o[c4*4+0], o[c4*4+1], o[c4*4+2], o[c4*4+3]);
}

// ---------------- launch ----------------

extern "C" void kernel_launch(void* const* d_in, const int* in_sizes, int n_in,
                              void* d_out, int out_size, void* d_ws, size_t ws_size,
                              hipStream_t stream) {
  const float* x   = (const float*)d_in[0];
  const int*   ei  = (const int*)d_in[1];
  const float* ea  = (const float*)d_in[2];
  const float* ew1 = (const float*)d_in[3];
  const float* eb1 = (const float*)d_in[4];
  const float* ew2 = (const float*)d_in[5];
  const float* eb2 = (const float*)d_in[6];
  const float* nw1 = (const float*)d_in[7];
  const float* nb1 = (const float*)d_in[8];
  const float* nw2 = (const float*)d_in[9];
  const float* nb2 = (const float*)d_in[10];
  float* out = (float*)d_out;

  const int N = in_sizes[0] / 64;   // 100000
  const int E = in_sizes[1] / 2;    // 1600000

  // workspace layout
  float* U  = (float*)d_ws;                       // N*64 f32
  float* V  = U + (size_t)N * 64;                 // N*64 f32
  int* ib   = (int*)(V + (size_t)N * 64);
  int* deg  = ib;                                 // N
  int* cur  = ib + N;                             // N
  int* bsum = ib + 2 * N;                         // <=512
  int* boff = ib + 2 * N + 512;                   // <=512
  int* eid  = ib + 2 * N + 1024;                  // E
  float* H  = out;                                // H lives in d_out

  const int NT = (N + 3) / 4;
  const int NB = (NT + TPB - 1) / TPB;

  hipMemsetAsync(deg, 0, (size_t)N * sizeof(int), stream);

  k_hist<<<(E + TPB - 1) / TPB, TPB, 0, stream>>>(ei, deg, E);
  k_red<<<NB, TPB, 0, stream>>>(deg, bsum, N);
  k_scanb<<<1, 64, 0, stream>>>(bsum, boff, NB);
  k_apply<<<NB, TPB, 0, stream>>>(deg, boff, cur, N);
  k_scatter<<<(E + TPB - 1) / TPB, TPB, 0, stream>>>(ei, cur, eid, E);

  {
    const int nwaves = 2 * ((N + 63) / 64);
    const int nblocks = (nwaves + 3) / 4;
    k_prep2<<<nblocks, TPB, 0, stream>>>(x, ew1, eb1, U, V, N);
  }

  k_edge3<<<(N + 3) / 4, TPB, 0, stream>>>(
      U, V, ea, ei, ew1, deg, cur, eid, H, N, E);

  k_node2<<<(N + TPB - 1) / TPB, TPB, 0, stream>>>(
      x, H, deg, ew2, eb2, nw1, nb1, nw2, nb2, out, N);
}